// Round 1
// baseline (632.015 us; speedup 1.0000x reference)
//
#include <hip/hip_runtime.h>
#include <math.h>

// ReDrafterHead: B=64, H=4096, D=512, G3=1536, V=32000, STEPS=4
// Round 1: correct fp32 baseline, multi-kernel, deterministic (no atomics).

#define KC 32

// ---------------------------------------------------------------------------
// Generic 64(M) x 64(N) tile GEMM: C[m][n0+n] = sum_{k0..k0+klen} A[m][k]*W[n0+n][k]
// block = 256 threads, micro-tile 4x4 per thread.
// ---------------------------------------------------------------------------
__device__ __forceinline__ void gemm64_tile(
    const float* __restrict__ A, int lda,
    const float* __restrict__ W, int ldb,
    int n0, int k0, int klen,
    float* __restrict__ C, int ldc,
    float* As, float* Bs)
{
    const int tid = threadIdx.x;
    const int tm = tid >> 4;   // 0..15 -> m = tm*4
    const int tn = tid & 15;   // 0..15 -> n = tn*4
    float acc[4][4];
#pragma unroll
    for (int i = 0; i < 4; ++i)
#pragma unroll
        for (int j = 0; j < 4; ++j) acc[i][j] = 0.f;

    for (int kk = k0; kk < k0 + klen; kk += KC) {
        // Load A chunk: 64 rows x 32 k = 512 float4, 2 per thread
#pragma unroll
        for (int r = 0; r < 2; ++r) {
            int idx = r * 256 + tid;
            int m = idx >> 3;
            int q = idx & 7;
            float4 v = *(const float4*)(A + m * lda + kk + q * 4);
            float* p = As + (q * 4) * 68 + m;
            p[0] = v.x; p[68] = v.y; p[136] = v.z; p[204] = v.w;
        }
        // Load B chunk: 64 rows x 32 k
#pragma unroll
        for (int r = 0; r < 2; ++r) {
            int idx = r * 256 + tid;
            int n = idx >> 3;
            int q = idx & 7;
            float4 v = *(const float4*)(W + (n0 + n) * ldb + kk + q * 4);
            float* p = Bs + (q * 4) * 68 + n;
            p[0] = v.x; p[68] = v.y; p[136] = v.z; p[204] = v.w;
        }
        __syncthreads();
#pragma unroll
        for (int k = 0; k < KC; ++k) {
            float4 a = *(const float4*)(As + k * 68 + tm * 4);
            float4 b = *(const float4*)(Bs + k * 68 + tn * 4);
            acc[0][0] += a.x * b.x; acc[0][1] += a.x * b.y; acc[0][2] += a.x * b.z; acc[0][3] += a.x * b.w;
            acc[1][0] += a.y * b.x; acc[1][1] += a.y * b.y; acc[1][2] += a.y * b.z; acc[1][3] += a.y * b.w;
            acc[2][0] += a.z * b.x; acc[2][1] += a.z * b.y; acc[2][2] += a.z * b.z; acc[2][3] += a.z * b.w;
            acc[3][0] += a.w * b.x; acc[3][1] += a.w * b.y; acc[3][2] += a.w * b.z; acc[3][3] += a.w * b.w;
        }
        __syncthreads();
    }
#pragma unroll
    for (int i = 0; i < 4; ++i) {
        float* cp = C + (tm * 4 + i) * ldc + n0 + tn * 4;
        *(float4*)cp = make_float4(acc[i][0], acc[i][1], acc[i][2], acc[i][3]);
    }
}

// ---------------------------------------------------------------------------
// in_proj: h0 = hidden[64,4096] @ in_proj_w[512,4096]^T, K-split=8 partials
// grid = 64 blocks: nt = bx&7 (n-tile of 64), ks = bx>>3 (k-split of 512)
// ---------------------------------------------------------------------------
__global__ __launch_bounds__(256) void k_inproj(
    const float* __restrict__ A, const float* __restrict__ W,
    float* __restrict__ part)
{
    __shared__ alignas(16) float As[KC * 68];
    __shared__ alignas(16) float Bs[KC * 68];
    int bx = blockIdx.x;
    int nt = bx & 7;
    int ks = bx >> 3;
    gemm64_tile(A, 4096, W, 4096, nt * 64, ks * 512, 512,
                part + ks * (64 * 512), 512, As, Bs);
}

// part: [8][64][512] -> hA = hB = sum + bias; also zero x buffer
__global__ __launch_bounds__(256) void k_reduce_inproj(
    const float* __restrict__ part, const float* __restrict__ bias,
    float* __restrict__ hA, float* __restrict__ hB, float* __restrict__ xb)
{
    int i = blockIdx.x * 256 + threadIdx.x;   // < 32768
    int d = i & 511;
    float s = bias[d];
#pragma unroll
    for (int ks = 0; ks < 8; ++ks) s += part[ks * 32768 + i];
    hA[i] = s;
    hB[i] = s;
    xb[i] = 0.f;
}

// ---------------------------------------------------------------------------
// GRU gates: gi = xv @ w_ih^T, gh = hv @ w_hh^T  (both [64,1536]), K-split=4
// grid = 192: nt = bx%24, ks = (bx/24)&3, mat = bx/96 (0: gi, 1: gh)
// partial layout: [ks][64][1536]
// ---------------------------------------------------------------------------
__global__ __launch_bounds__(256) void k_gates(
    const float* __restrict__ xv, const float* __restrict__ hv,
    const float* __restrict__ w_ih, const float* __restrict__ w_hh,
    float* __restrict__ gip, float* __restrict__ ghp)
{
    __shared__ alignas(16) float As[KC * 68];
    __shared__ alignas(16) float Bs[KC * 68];
    int bx = blockIdx.x;
    int nt = bx % 24;
    int ks = (bx / 24) & 3;
    int mat = bx / 96;
    const float* A = mat ? hv : xv;
    const float* W = mat ? w_hh : w_ih;
    float* C = mat ? ghp : gip;
    gemm64_tile(A, 512, W, 512, nt * 64, ks * 128, 128,
                C + ks * (64 * 1536), 1536, As, Bs);
}

// GRU combine: reduce K-split partials + biases, apply gates, h updated in place
__global__ __launch_bounds__(256) void k_combine(
    const float* __restrict__ gip, const float* __restrict__ ghp,
    const float* __restrict__ b_ih, const float* __restrict__ b_hh,
    float* __restrict__ h)
{
    int i = blockIdx.x * 256 + threadIdx.x;   // < 32768
    int b = i >> 9;
    int d = i & 511;
    float ir = b_ih[d], iz = b_ih[d + 512], inn = b_ih[d + 1024];
    float hr = b_hh[d], hz = b_hh[d + 512], hn = b_hh[d + 1024];
    int base = b * 1536 + d;
#pragma unroll
    for (int s = 0; s < 4; ++s) {
        const float* g  = gip + s * 98304 + base;
        const float* gg = ghp + s * 98304 + base;
        ir  += g[0];    iz += g[512];    inn += g[1024];
        hr  += gg[0];   hz += gg[512];   hn  += gg[1024];
    }
    float r = 1.f / (1.f + expf(-(ir + hr)));
    float z = 1.f / (1.f + expf(-(iz + hz)));
    float n = tanhf(inn + r * hn);
    h[i] = (1.f - z) * n + z * h[i];
}

// ---------------------------------------------------------------------------
// logits: C[64,32000] = h[64,512] @ out_w[32000,512]^T
// tile 64(M) x 128(N), micro 4x8, 250 blocks. Writes into d_out[b][step][v].
// ---------------------------------------------------------------------------
__global__ __launch_bounds__(256) void k_logits(
    const float* __restrict__ h, const float* __restrict__ W,
    float* __restrict__ out, int step)
{
    __shared__ alignas(16) float As[KC * 68];
    __shared__ alignas(16) float Bs[KC * 132];
    const int tid = threadIdx.x;
    const int n0 = blockIdx.x * 128;
    const int tm = tid >> 4;   // 0..15 -> m = tm*4
    const int tn = tid & 15;   // 0..15 -> n = tn*8
    float acc[4][8];
#pragma unroll
    for (int i = 0; i < 4; ++i)
#pragma unroll
        for (int j = 0; j < 8; ++j) acc[i][j] = 0.f;

    for (int kk = 0; kk < 512; kk += KC) {
#pragma unroll
        for (int r = 0; r < 2; ++r) {
            int idx = r * 256 + tid;
            int m = idx >> 3;
            int q = idx & 7;
            float4 v = *(const float4*)(h + m * 512 + kk + q * 4);
            float* p = As + (q * 4) * 68 + m;
            p[0] = v.x; p[68] = v.y; p[136] = v.z; p[204] = v.w;
        }
#pragma unroll
        for (int r = 0; r < 4; ++r) {
            int idx = r * 256 + tid;
            int n = idx >> 3;
            int q = idx & 7;
            float4 v = *(const float4*)(W + (n0 + n) * 512 + kk + q * 4);
            float* p = Bs + (q * 4) * 132 + n;
            p[0] = v.x; p[132] = v.y; p[264] = v.z; p[396] = v.w;
        }
        __syncthreads();
#pragma unroll
        for (int k = 0; k < KC; ++k) {
            float4 a  = *(const float4*)(As + k * 68 + tm * 4);
            float4 b0 = *(const float4*)(Bs + k * 132 + tn * 8);
            float4 b1 = *(const float4*)(Bs + k * 132 + tn * 8 + 4);
            acc[0][0] += a.x * b0.x; acc[0][1] += a.x * b0.y; acc[0][2] += a.x * b0.z; acc[0][3] += a.x * b0.w;
            acc[0][4] += a.x * b1.x; acc[0][5] += a.x * b1.y; acc[0][6] += a.x * b1.z; acc[0][7] += a.x * b1.w;
            acc[1][0] += a.y * b0.x; acc[1][1] += a.y * b0.y; acc[1][2] += a.y * b0.z; acc[1][3] += a.y * b0.w;
            acc[1][4] += a.y * b1.x; acc[1][5] += a.y * b1.y; acc[1][6] += a.y * b1.z; acc[1][7] += a.y * b1.w;
            acc[2][0] += a.z * b0.x; acc[2][1] += a.z * b0.y; acc[2][2] += a.z * b0.z; acc[2][3] += a.z * b0.w;
            acc[2][4] += a.z * b1.x; acc[2][5] += a.z * b1.y; acc[2][6] += a.z * b1.z; acc[2][7] += a.z * b1.w;
            acc[3][0] += a.w * b0.x; acc[3][1] += a.w * b0.y; acc[3][2] += a.w * b0.z; acc[3][3] += a.w * b0.w;
            acc[3][4] += a.w * b1.x; acc[3][5] += a.w * b1.y; acc[3][6] += a.w * b1.z; acc[3][7] += a.w * b1.w;
        }
        __syncthreads();
    }
#pragma unroll
    for (int i = 0; i < 4; ++i) {
        float* cp = out + (tm * 4 + i) * 128000 + step * 32000 + n0 + tn * 8;
        *(float4*)cp       = make_float4(acc[i][0], acc[i][1], acc[i][2], acc[i][3]);
        *(float4*)(cp + 4) = make_float4(acc[i][4], acc[i][5], acc[i][6], acc[i][7]);
    }
}

// ---------------------------------------------------------------------------
// argmax per batch row (np.argmax semantics: first occurrence of max) + embed
// gather into x buffer. grid = 64 blocks (one per b).
// ---------------------------------------------------------------------------
__global__ __launch_bounds__(256) void k_argmax_embed(
    const float* __restrict__ out, int step,
    const float* __restrict__ embed, float* __restrict__ xb)
{
    __shared__ float sv[256];
    __shared__ int   si[256];
    const int b = blockIdx.x;
    const int tid = threadIdx.x;
    const float* row = out + b * 128000 + step * 32000;
    float best = -3.4e38f;
    int bi = 0x7fffffff;
    for (int i = tid; i < 32000; i += 256) {
        float v = row[i];
        if (v > best || (v == best && i < bi)) { best = v; bi = i; }
    }
    sv[tid] = best;
    si[tid] = bi;
    __syncthreads();
    for (int s = 128; s > 0; s >>= 1) {
        if (tid < s) {
            float ov = sv[tid + s];
            int oi = si[tid + s];
            if (ov > sv[tid] || (ov == sv[tid] && oi < si[tid])) { sv[tid] = ov; si[tid] = oi; }
        }
        __syncthreads();
    }
    int tok = si[0];
    for (int j = tid; j < 512; j += 256)
        xb[b * 512 + j] = embed[tok * 512 + j];
}

// ---------------------------------------------------------------------------
extern "C" void kernel_launch(void* const* d_in, const int* in_sizes, int n_in,
                              void* d_out, int out_size, void* d_ws, size_t ws_size,
                              hipStream_t stream)
{
    const float* hidden = (const float*)d_in[0];   // [64, 4096]
    const float* in_w   = (const float*)d_in[1];   // [512, 4096]
    const float* in_b   = (const float*)d_in[2];   // [512]
    const float* w_ih0  = (const float*)d_in[3];   // [1536, 512]
    const float* w_hh0  = (const float*)d_in[4];
    const float* b_ih0  = (const float*)d_in[5];
    const float* b_hh0  = (const float*)d_in[6];
    const float* w_ih1  = (const float*)d_in[7];
    const float* w_hh1  = (const float*)d_in[8];
    const float* b_ih1  = (const float*)d_in[9];
    const float* b_hh1  = (const float*)d_in[10];
    const float* embed  = (const float*)d_in[11];  // [32000, 512]
    const float* out_w  = (const float*)d_in[12];  // [32000, 512]
    float* out = (float*)d_out;                    // [64, 4, 32000]
    float* ws  = (float*)d_ws;

    // ws layout (floats): hA[32768] hB[32768] x[32768] gip[4*98304] ghp[4*98304]
    float* hA  = ws;
    float* hB  = ws + 32768;
    float* xb  = ws + 65536;
    float* gip = ws + 98304;
    float* ghp = gip + 393216;
    float* ipart = gip;   // reuse gi partial space for in_proj partials (8*32768)

    k_inproj<<<64, 256, 0, stream>>>(hidden, in_w, ipart);
    k_reduce_inproj<<<128, 256, 0, stream>>>(ipart, in_b, hA, hB, xb);

    for (int step = 0; step < 4; ++step) {
        // layer 0: x -> hA
        k_gates<<<192, 256, 0, stream>>>(xb, hA, w_ih0, w_hh0, gip, ghp);
        k_combine<<<128, 256, 0, stream>>>(gip, ghp, b_ih0, b_hh0, hA);
        // layer 1: hA -> hB
        k_gates<<<192, 256, 0, stream>>>(hA, hB, w_ih1, w_hh1, gip, ghp);
        k_combine<<<128, 256, 0, stream>>>(gip, ghp, b_ih1, b_hh1, hB);
        // logits + argmax + embed gather
        k_logits<<<250, 256, 0, stream>>>(hB, out_w, out, step);
        k_argmax_embed<<<64, 256, 0, stream>>>(out, step, embed, xb);
    }
}

// Round 2
// 604.562 us; speedup vs baseline: 1.0454x; 1.0454x over previous
//
#include <hip/hip_runtime.h>
#include <math.h>

// ReDrafterHead: B=64, H=4096, D=512, G3=1536, V=32000, STEPS=4
// Round 2: split-bf16 MFMA GEMMs (3-pass hi/lo), in-kernel fp32->bf16 split.

typedef __attribute__((ext_vector_type(8))) short short8;   // 8 bf16 (4 VGPRs)
typedef __attribute__((ext_vector_type(4))) float f32x4;    // MFMA accumulator

#define KT  64   // k-tile
#define LDT 72   // padded LDS row stride (bf16 elems): 144 B, breaks pow2 conflicts

__device__ __forceinline__ unsigned short f2bf_rne(float x) {
    unsigned u = __float_as_uint(x);
    unsigned r = (u + 0x7fffu + ((u >> 16) & 1u)) >> 16;
    return (unsigned short)r;
}
__device__ __forceinline__ float bf2f(unsigned short h) {
    return __uint_as_float(((unsigned)h) << 16);
}
__device__ __forceinline__ void split2(float x, unsigned short& hi, unsigned short& lo) {
    hi = f2bf_rne(x);
    lo = f2bf_rne(x - bf2f(hi));
}

// ---------------------------------------------------------------------------
// Generic MFMA GEMM: C[0..63][n0..n0+127] (+)= A[64 x K] @ W[N x K]^T over
// k in [k0, k0+klen). block = 256 threads (4 waves). Split-bf16, fp32 acc.
// Wave w covers n-slice [w*32, (w+1)*32) of the 128-wide tile, full M=64.
// ---------------------------------------------------------------------------
__device__ __forceinline__ void mfma_gemm_64x128(
    const float* __restrict__ A, int lda,
    const float* __restrict__ W, int ldb,
    int n0, int k0, int klen,
    float* __restrict__ C, int ldc,
    unsigned short* AsH, unsigned short* AsL,
    unsigned short* BsH, unsigned short* BsL)
{
    const int tid  = threadIdx.x;
    const int wv   = tid >> 6;
    const int lane = tid & 63;
    const int lr   = lane & 15;   // row within 16-tile
    const int lh   = lane >> 4;   // quad 0..3

    f32x4 acc[4][2];
#pragma unroll
    for (int i = 0; i < 4; ++i)
#pragma unroll
        for (int j = 0; j < 2; ++j) acc[i][j] = (f32x4){0.f, 0.f, 0.f, 0.f};

    for (int kk = k0; kk < k0 + klen; kk += KT) {
        // ---- stage A: 64 x 64 fp32 -> hi/lo bf16 planes ----
#pragma unroll
        for (int r = 0; r < 4; ++r) {
            int idx = r * 256 + tid;       // 0..1023 float4 slots
            int m = idx >> 4;              // 64 rows
            int q = idx & 15;              // 16 float4 per row
            float4 v = *(const float4*)(A + m * lda + kk + q * 4);
            unsigned short h0,h1,h2,h3,l0,l1,l2,l3;
            split2(v.x,h0,l0); split2(v.y,h1,l1); split2(v.z,h2,l2); split2(v.w,h3,l3);
            uint2 ph = make_uint2((unsigned)h0 | ((unsigned)h1 << 16),
                                  (unsigned)h2 | ((unsigned)h3 << 16));
            uint2 pl = make_uint2((unsigned)l0 | ((unsigned)l1 << 16),
                                  (unsigned)l2 | ((unsigned)l3 << 16));
            *(uint2*)(AsH + m * LDT + q * 4) = ph;
            *(uint2*)(AsL + m * LDT + q * 4) = pl;
        }
        // ---- stage B: 128 x 64 fp32 -> hi/lo bf16 planes ----
#pragma unroll
        for (int r = 0; r < 8; ++r) {
            int idx = r * 256 + tid;       // 0..2047 float4 slots
            int n = idx >> 4;              // 128 rows
            int q = idx & 15;
            float4 v = *(const float4*)(W + (n0 + n) * ldb + kk + q * 4);
            unsigned short h0,h1,h2,h3,l0,l1,l2,l3;
            split2(v.x,h0,l0); split2(v.y,h1,l1); split2(v.z,h2,l2); split2(v.w,h3,l3);
            uint2 ph = make_uint2((unsigned)h0 | ((unsigned)h1 << 16),
                                  (unsigned)h2 | ((unsigned)h3 << 16));
            uint2 pl = make_uint2((unsigned)l0 | ((unsigned)l1 << 16),
                                  (unsigned)l2 | ((unsigned)l3 << 16));
            *(uint2*)(BsH + n * LDT + q * 4) = ph;
            *(uint2*)(BsL + n * LDT + q * 4) = pl;
        }
        __syncthreads();

        // ---- MFMA over two K=32 halves ----
#pragma unroll
        for (int kk2 = 0; kk2 < 2; ++kk2) {
            const int ko = kk2 * 32 + lh * 8;
            short8 ah[4], al[4];
#pragma unroll
            for (int mt = 0; mt < 4; ++mt) {
                ah[mt] = *(const short8*)(AsH + (mt * 16 + lr) * LDT + ko);
                al[mt] = *(const short8*)(AsL + (mt * 16 + lr) * LDT + ko);
            }
            short8 bh[2], bl[2];
#pragma unroll
            for (int nt = 0; nt < 2; ++nt) {
                bh[nt] = *(const short8*)(BsH + (wv * 32 + nt * 16 + lr) * LDT + ko);
                bl[nt] = *(const short8*)(BsL + (wv * 32 + nt * 16 + lr) * LDT + ko);
            }
#pragma unroll
            for (int mt = 0; mt < 4; ++mt)
#pragma unroll
                for (int nt = 0; nt < 2; ++nt) {
                    acc[mt][nt] = __builtin_amdgcn_mfma_f32_16x16x32_bf16(ah[mt], bh[nt], acc[mt][nt], 0, 0, 0);
                    acc[mt][nt] = __builtin_amdgcn_mfma_f32_16x16x32_bf16(ah[mt], bl[nt], acc[mt][nt], 0, 0, 0);
                    acc[mt][nt] = __builtin_amdgcn_mfma_f32_16x16x32_bf16(al[mt], bh[nt], acc[mt][nt], 0, 0, 0);
                }
        }
        __syncthreads();
    }
    // ---- epilogue: D mapping col=lane&15, row=(lane>>4)*4+i ----
#pragma unroll
    for (int mt = 0; mt < 4; ++mt)
#pragma unroll
        for (int nt = 0; nt < 2; ++nt) {
            int n = n0 + wv * 32 + nt * 16 + lr;
#pragma unroll
            for (int i = 0; i < 4; ++i) {
                int m = mt * 16 + lh * 4 + i;
                C[m * ldc + n] = acc[mt][nt][i];
            }
        }
}

#define DECLARE_LDS() \
    __shared__ alignas(16) unsigned short AsH[64 * LDT]; \
    __shared__ alignas(16) unsigned short AsL[64 * LDT]; \
    __shared__ alignas(16) unsigned short BsH[128 * LDT]; \
    __shared__ alignas(16) unsigned short BsL[128 * LDT];

// ---------------------------------------------------------------------------
// in_proj: part[ks][64][512] = hidden[64,4096] @ in_w[512,4096]^T, K-split 8
// grid = 32: nt = bx&3 (n-tile of 128), ks = bx>>2
// ---------------------------------------------------------------------------
__global__ __launch_bounds__(256) void k_inproj(
    const float* __restrict__ A, const float* __restrict__ W,
    float* __restrict__ part)
{
    DECLARE_LDS();
    int nt = blockIdx.x & 3;
    int ks = blockIdx.x >> 2;
    mfma_gemm_64x128(A, 4096, W, 4096, nt * 128, ks * 512, 512,
                     part + ks * 32768, 512, AsH, AsL, BsH, BsL);
}

__global__ __launch_bounds__(256) void k_reduce_inproj(
    const float* __restrict__ part, const float* __restrict__ bias,
    float* __restrict__ hA, float* __restrict__ hB, float* __restrict__ xb)
{
    int i = blockIdx.x * 256 + threadIdx.x;   // < 32768
    int d = i & 511;
    float s = bias[d];
#pragma unroll
    for (int ks = 0; ks < 8; ++ks) s += part[ks * 32768 + i];
    hA[i] = s;
    hB[i] = s;
    xb[i] = 0.f;
}

// ---------------------------------------------------------------------------
// GRU gates: gi = xv @ w_ih^T, gh = hv @ w_hh^T  (both [64,1536]), no K-split
// grid = 24: bx<12 -> gi tile bx, else gh tile bx-12
// ---------------------------------------------------------------------------
__global__ __launch_bounds__(256) void k_gates(
    const float* __restrict__ xv, const float* __restrict__ hv,
    const float* __restrict__ w_ih, const float* __restrict__ w_hh,
    float* __restrict__ gi, float* __restrict__ gh)
{
    DECLARE_LDS();
    int bx = blockIdx.x;
    const float* A = (bx < 12) ? xv : hv;
    const float* W = (bx < 12) ? w_ih : w_hh;
    float* C = (bx < 12) ? gi : gh;
    int nt = (bx < 12) ? bx : (bx - 12);
    mfma_gemm_64x128(A, 512, W, 512, nt * 128, 0, 512, C, 1536,
                     AsH, AsL, BsH, BsL);
}

__global__ __launch_bounds__(256) void k_combine(
    const float* __restrict__ gi, const float* __restrict__ gh,
    const float* __restrict__ b_ih, const float* __restrict__ b_hh,
    float* __restrict__ h)
{
    int i = blockIdx.x * 256 + threadIdx.x;   // < 32768
    int b = i >> 9;
    int d = i & 511;
    int base = b * 1536 + d;
    float ir = gi[base]        + b_ih[d];
    float iz = gi[base + 512]  + b_ih[d + 512];
    float inn= gi[base + 1024] + b_ih[d + 1024];
    float hr = gh[base]        + b_hh[d];
    float hz = gh[base + 512]  + b_hh[d + 512];
    float hn = gh[base + 1024] + b_hh[d + 1024];
    float r = 1.f / (1.f + expf(-(ir + hr)));
    float z = 1.f / (1.f + expf(-(iz + hz)));
    float n = tanhf(inn + r * hn);
    h[i] = (1.f - z) * n + z * h[i];
}

// ---------------------------------------------------------------------------
// logits: out[b][step][n0..] = h[64,512] @ out_w[32000,512]^T, grid = 250
// ---------------------------------------------------------------------------
__global__ __launch_bounds__(256) void k_logits(
    const float* __restrict__ h, const float* __restrict__ W,
    float* __restrict__ out, int step)
{
    DECLARE_LDS();
    mfma_gemm_64x128(h, 512, W, 512, blockIdx.x * 128, 0, 512,
                     out + step * 32000, 128000, AsH, AsL, BsH, BsL);
}

// ---------------------------------------------------------------------------
// argmax per batch row (np first-occurrence semantics) + embed gather
// ---------------------------------------------------------------------------
__global__ __launch_bounds__(256) void k_argmax_embed(
    const float* __restrict__ out, int step,
    const float* __restrict__ embed, float* __restrict__ xb)
{
    __shared__ float sv[256];
    __shared__ int   si[256];
    const int b = blockIdx.x;
    const int tid = threadIdx.x;
    const float* row = out + b * 128000 + step * 32000;
    float best = -3.4e38f;
    int bi = 0x7fffffff;
    for (int i = tid; i < 32000; i += 256) {
        float v = row[i];
        if (v > best || (v == best && i < bi)) { best = v; bi = i; }
    }
    sv[tid] = best;
    si[tid] = bi;
    __syncthreads();
    for (int s = 128; s > 0; s >>= 1) {
        if (tid < s) {
            float ov = sv[tid + s];
            int oi = si[tid + s];
            if (ov > sv[tid] || (ov == sv[tid] && oi < si[tid])) { sv[tid] = ov; si[tid] = oi; }
        }
        __syncthreads();
    }
    int tok = si[0];
    for (int j = tid; j < 512; j += 256)
        xb[b * 512 + j] = embed[tok * 512 + j];
}

// ---------------------------------------------------------------------------
extern "C" void kernel_launch(void* const* d_in, const int* in_sizes, int n_in,
                              void* d_out, int out_size, void* d_ws, size_t ws_size,
                              hipStream_t stream)
{
    const float* hidden = (const float*)d_in[0];   // [64, 4096]
    const float* in_w   = (const float*)d_in[1];   // [512, 4096]
    const float* in_b   = (const float*)d_in[2];   // [512]
    const float* w_ih0  = (const float*)d_in[3];   // [1536, 512]
    const float* w_hh0  = (const float*)d_in[4];
    const float* b_ih0  = (const float*)d_in[5];
    const float* b_hh0  = (const float*)d_in[6];
    const float* w_ih1  = (const float*)d_in[7];
    const float* w_hh1  = (const float*)d_in[8];
    const float* b_ih1  = (const float*)d_in[9];
    const float* b_hh1  = (const float*)d_in[10];
    const float* embed  = (const float*)d_in[11];  // [32000, 512]
    const float* out_w  = (const float*)d_in[12];  // [32000, 512]
    float* out = (float*)d_out;                    // [64, 4, 32000]
    float* ws  = (float*)d_ws;

    // ws layout (floats): hA[32768] hB[32768] x[32768] gi[98304] gh[98304]
    float* hA = ws;
    float* hB = ws + 32768;
    float* xb = ws + 65536;
    float* gi = ws + 98304;
    float* gh = gi + 98304;
    float* ipart = gi;   // reuse gi/gh region for in_proj partials (8*32768 floats)

    k_inproj<<<32, 256, 0, stream>>>(hidden, in_w, ipart);
    k_reduce_inproj<<<128, 256, 0, stream>>>(ipart, in_b, hA, hB, xb);

    for (int step = 0; step < 4; ++step) {
        // layer 0: x -> hA
        k_gates<<<24, 256, 0, stream>>>(xb, hA, w_ih0, w_hh0, gi, gh);
        k_combine<<<128, 256, 0, stream>>>(gi, gh, b_ih0, b_hh0, hA);
        // layer 1: hA -> hB
        k_gates<<<24, 256, 0, stream>>>(hA, hB, w_ih1, w_hh1, gi, gh);
        k_combine<<<128, 256, 0, stream>>>(gi, gh, b_ih1, b_hh1, hB);
        // logits + argmax + embed gather
        k_logits<<<250, 256, 0, stream>>>(hB, out_w, out, step);
        k_argmax_embed<<<64, 256, 0, stream>>>(out, step, embed, xb);
    }
}

// Round 3
// 473.974 us; speedup vs baseline: 1.3334x; 1.2755x over previous
//
#include <hip/hip_runtime.h>
#include <math.h>

// ReDrafterHead: B=64, H=4096, D=512, G3=1536, V=32000, STEPS=4
// Round 3: argmax fused into k_logits epilogue (partials) + tiny reduce+embed
// kernel. Cheaper fp32->hi/lo bf16 split (trunc hi + RNE lo).

typedef __attribute__((ext_vector_type(8))) short short8;   // 8 bf16 (4 VGPRs)
typedef __attribute__((ext_vector_type(4))) float f32x4;    // MFMA accumulator

#define KT  64   // k-tile
#define LDT 72   // padded LDS row stride (bf16 elems) — breaks pow2 conflicts

__device__ __forceinline__ unsigned short f2bf_rne(float x) {
    unsigned u = __float_as_uint(x);
    unsigned r = (u + 0x7fffu + ((u >> 16) & 1u)) >> 16;
    return (unsigned short)r;
}
// hi = truncate to bf16 (cheap); lo = RNE of residual. |err| ~ 2^-16 rel.
__device__ __forceinline__ void split2(float x, unsigned short& hi, unsigned short& lo) {
    unsigned u = __float_as_uint(x);
    hi = (unsigned short)(u >> 16);
    float r = x - __uint_as_float(u & 0xffff0000u);
    lo = f2bf_rne(r);
}

// ---------------------------------------------------------------------------
// MFMA GEMM: C[0..63][n0..n0+127] = A[64 x K] @ W[N x K]^T over [k0,k0+klen).
// block = 256 threads (4 waves); wave w covers n-slice [w*32,(w+1)*32).
// Split-bf16 3-pass, fp32 accumulate. If ARGMAX, also writes per-block
// per-row (max,col) partials to pval/pidx at [bx*64 + row].
// ---------------------------------------------------------------------------
template<bool ARGMAX>
__device__ __forceinline__ void mfma_gemm_64x128(
    const float* __restrict__ A, int lda,
    const float* __restrict__ W, int ldb,
    int n0, int k0, int klen,
    float* __restrict__ C, int ldc,
    unsigned short* AsH, unsigned short* AsL,
    unsigned short* BsH, unsigned short* BsL,
    float* __restrict__ pval, int* __restrict__ pidx, int bx)
{
    const int tid  = threadIdx.x;
    const int wv   = tid >> 6;
    const int lane = tid & 63;
    const int lr   = lane & 15;   // row within 16-tile
    const int lh   = lane >> 4;   // quad 0..3

    f32x4 acc[4][2];
#pragma unroll
    for (int i = 0; i < 4; ++i)
#pragma unroll
        for (int j = 0; j < 2; ++j) acc[i][j] = (f32x4){0.f, 0.f, 0.f, 0.f};

    for (int kk = k0; kk < k0 + klen; kk += KT) {
        // ---- stage A: 64 x 64 fp32 -> hi/lo bf16 planes ----
#pragma unroll
        for (int r = 0; r < 4; ++r) {
            int idx = r * 256 + tid;       // 0..1023 float4 slots
            int m = idx >> 4;
            int q = idx & 15;
            float4 v = *(const float4*)(A + m * lda + kk + q * 4);
            unsigned short h0,h1,h2,h3,l0,l1,l2,l3;
            split2(v.x,h0,l0); split2(v.y,h1,l1); split2(v.z,h2,l2); split2(v.w,h3,l3);
            uint2 ph = make_uint2((unsigned)h0 | ((unsigned)h1 << 16),
                                  (unsigned)h2 | ((unsigned)h3 << 16));
            uint2 pl = make_uint2((unsigned)l0 | ((unsigned)l1 << 16),
                                  (unsigned)l2 | ((unsigned)l3 << 16));
            *(uint2*)(AsH + m * LDT + q * 4) = ph;
            *(uint2*)(AsL + m * LDT + q * 4) = pl;
        }
        // ---- stage B: 128 x 64 fp32 -> hi/lo bf16 planes ----
#pragma unroll
        for (int r = 0; r < 8; ++r) {
            int idx = r * 256 + tid;       // 0..2047 float4 slots
            int n = idx >> 4;
            int q = idx & 15;
            float4 v = *(const float4*)(W + (n0 + n) * ldb + kk + q * 4);
            unsigned short h0,h1,h2,h3,l0,l1,l2,l3;
            split2(v.x,h0,l0); split2(v.y,h1,l1); split2(v.z,h2,l2); split2(v.w,h3,l3);
            uint2 ph = make_uint2((unsigned)h0 | ((unsigned)h1 << 16),
                                  (unsigned)h2 | ((unsigned)h3 << 16));
            uint2 pl = make_uint2((unsigned)l0 | ((unsigned)l1 << 16),
                                  (unsigned)l2 | ((unsigned)l3 << 16));
            *(uint2*)(BsH + n * LDT + q * 4) = ph;
            *(uint2*)(BsL + n * LDT + q * 4) = pl;
        }
        __syncthreads();

#pragma unroll
        for (int kk2 = 0; kk2 < 2; ++kk2) {
            const int ko = kk2 * 32 + lh * 8;
            short8 ah[4], al[4];
#pragma unroll
            for (int mt = 0; mt < 4; ++mt) {
                ah[mt] = *(const short8*)(AsH + (mt * 16 + lr) * LDT + ko);
                al[mt] = *(const short8*)(AsL + (mt * 16 + lr) * LDT + ko);
            }
            short8 bh[2], bl[2];
#pragma unroll
            for (int nt = 0; nt < 2; ++nt) {
                bh[nt] = *(const short8*)(BsH + (wv * 32 + nt * 16 + lr) * LDT + ko);
                bl[nt] = *(const short8*)(BsL + (wv * 32 + nt * 16 + lr) * LDT + ko);
            }
#pragma unroll
            for (int mt = 0; mt < 4; ++mt)
#pragma unroll
                for (int nt = 0; nt < 2; ++nt) {
                    acc[mt][nt] = __builtin_amdgcn_mfma_f32_16x16x32_bf16(ah[mt], bh[nt], acc[mt][nt], 0, 0, 0);
                    acc[mt][nt] = __builtin_amdgcn_mfma_f32_16x16x32_bf16(ah[mt], bl[nt], acc[mt][nt], 0, 0, 0);
                    acc[mt][nt] = __builtin_amdgcn_mfma_f32_16x16x32_bf16(al[mt], bh[nt], acc[mt][nt], 0, 0, 0);
                }
        }
        __syncthreads();
    }
    // ---- epilogue: D mapping col=lane&15, row=(lane>>4)*4+i ----
#pragma unroll
    for (int mt = 0; mt < 4; ++mt)
#pragma unroll
        for (int nt = 0; nt < 2; ++nt) {
            int n = n0 + wv * 32 + nt * 16 + lr;
#pragma unroll
            for (int i = 0; i < 4; ++i) {
                int m = mt * 16 + lh * 4 + i;
                C[m * ldc + n] = acc[mt][nt][i];
            }
        }

    if (ARGMAX) {
        // per-row partial argmax over this block's 128 cols.
        float* sv = (float*)AsH;     // [4][64] floats  (LDS reuse, safe after last sync)
        int*   sc = (int*)BsH;       // [4][64] ints
#pragma unroll
        for (int mt = 0; mt < 4; ++mt)
#pragma unroll
            for (int i = 0; i < 4; ++i) {
                float v = acc[mt][0][i];
                int   c = n0 + wv * 32 + lr;
                float v1 = acc[mt][1][i];
                if (v1 > v) { v = v1; c += 16; }   // tie -> keep lower col
#pragma unroll
                for (int m = 1; m < 16; m <<= 1) {
                    float ov = __shfl_xor(v, m, 64);
                    int   oc = __shfl_xor(c, m, 64);
                    if (ov > v || (ov == v && oc < c)) { v = ov; c = oc; }
                }
                if (lr == 0) {
                    int row = mt * 16 + lh * 4 + i;
                    sv[wv * 64 + row] = v;
                    sc[wv * 64 + row] = c;
                }
            }
        __syncthreads();
        if (tid < 64) {
            float v = sv[tid]; int c = sc[tid];
#pragma unroll
            for (int w = 1; w < 4; ++w) {
                float ov = sv[w * 64 + tid]; int oc = sc[w * 64 + tid];
                if (ov > v || (ov == v && oc < c)) { v = ov; c = oc; }
            }
            pval[bx * 64 + tid] = v;
            pidx[bx * 64 + tid] = c;
        }
    }
}

#define DECLARE_LDS() \
    __shared__ alignas(16) unsigned short AsH[64 * LDT]; \
    __shared__ alignas(16) unsigned short AsL[64 * LDT]; \
    __shared__ alignas(16) unsigned short BsH[128 * LDT]; \
    __shared__ alignas(16) unsigned short BsL[128 * LDT];

// ---------------------------------------------------------------------------
// in_proj: part[ks][64][512] = hidden[64,4096] @ in_w[512,4096]^T, K-split 8
// ---------------------------------------------------------------------------
__global__ __launch_bounds__(256) void k_inproj(
    const float* __restrict__ A, const float* __restrict__ W,
    float* __restrict__ part)
{
    DECLARE_LDS();
    int nt = blockIdx.x & 3;
    int ks = blockIdx.x >> 2;
    mfma_gemm_64x128<false>(A, 4096, W, 4096, nt * 128, ks * 512, 512,
                            part + ks * 32768, 512, AsH, AsL, BsH, BsL,
                            nullptr, nullptr, 0);
}

__global__ __launch_bounds__(256) void k_reduce_inproj(
    const float* __restrict__ part, const float* __restrict__ bias,
    float* __restrict__ hA, float* __restrict__ hB, float* __restrict__ xb)
{
    int i = blockIdx.x * 256 + threadIdx.x;   // < 32768
    int d = i & 511;
    float s = bias[d];
#pragma unroll
    for (int ks = 0; ks < 8; ++ks) s += part[ks * 32768 + i];
    hA[i] = s;
    hB[i] = s;
    xb[i] = 0.f;
}

// ---------------------------------------------------------------------------
// GRU gates: gi = xv @ w_ih^T, gh = hv @ w_hh^T (both [64,1536]), grid = 24
// ---------------------------------------------------------------------------
__global__ __launch_bounds__(256) void k_gates(
    const float* __restrict__ xv, const float* __restrict__ hv,
    const float* __restrict__ w_ih, const float* __restrict__ w_hh,
    float* __restrict__ gi, float* __restrict__ gh)
{
    DECLARE_LDS();
    int bx = blockIdx.x;
    const float* A = (bx < 12) ? xv : hv;
    const float* W = (bx < 12) ? w_ih : w_hh;
    float* C = (bx < 12) ? gi : gh;
    int nt = (bx < 12) ? bx : (bx - 12);
    mfma_gemm_64x128<false>(A, 512, W, 512, nt * 128, 0, 512, C, 1536,
                            AsH, AsL, BsH, BsL, nullptr, nullptr, 0);
}

__global__ __launch_bounds__(256) void k_combine(
    const float* __restrict__ gi, const float* __restrict__ gh,
    const float* __restrict__ b_ih, const float* __restrict__ b_hh,
    float* __restrict__ h)
{
    int i = blockIdx.x * 256 + threadIdx.x;   // < 32768
    int b = i >> 9;
    int d = i & 511;
    int base = b * 1536 + d;
    float ir = gi[base]        + b_ih[d];
    float iz = gi[base + 512]  + b_ih[d + 512];
    float inn= gi[base + 1024] + b_ih[d + 1024];
    float hr = gh[base]        + b_hh[d];
    float hz = gh[base + 512]  + b_hh[d + 512];
    float hn = gh[base + 1024] + b_hh[d + 1024];
    float r = 1.f / (1.f + expf(-(ir + hr)));
    float z = 1.f / (1.f + expf(-(iz + hz)));
    float n = tanhf(inn + r * hn);
    h[i] = (1.f - z) * n + z * h[i];
}

// ---------------------------------------------------------------------------
// logits + per-block argmax partials. grid = 250.
// ---------------------------------------------------------------------------
__global__ __launch_bounds__(256) void k_logits(
    const float* __restrict__ h, const float* __restrict__ W,
    float* __restrict__ out, int step,
    float* __restrict__ pval, int* __restrict__ pidx)
{
    DECLARE_LDS();
    mfma_gemm_64x128<true>(h, 512, W, 512, blockIdx.x * 128, 0, 512,
                           out + step * 32000, 128000, AsH, AsL, BsH, BsL,
                           pval, pidx, blockIdx.x);
}

// ---------------------------------------------------------------------------
// reduce 250 argmax partials per row (np first-occurrence) + embed gather
// ---------------------------------------------------------------------------
__global__ __launch_bounds__(256) void k_reduce_embed(
    const float* __restrict__ pval, const int* __restrict__ pidx,
    const float* __restrict__ embed, float* __restrict__ xb)
{
    __shared__ float sv[256];
    __shared__ int   sc[256];
    const int b = blockIdx.x;
    const int tid = threadIdx.x;
    float v = -3.4e38f;
    int   c = 0x7fffffff;
    if (tid < 250) { v = pval[tid * 64 + b]; c = pidx[tid * 64 + b]; }
    sv[tid] = v; sc[tid] = c;
    __syncthreads();
    for (int s = 128; s > 0; s >>= 1) {
        if (tid < s) {
            float ov = sv[tid + s]; int oc = sc[tid + s];
            if (ov > sv[tid] || (ov == sv[tid] && oc < sc[tid])) { sv[tid] = ov; sc[tid] = oc; }
        }
        __syncthreads();
    }
    int tok = sc[0];
    if (tid < 128) {
        float4 v4 = *(const float4*)(embed + tok * 512 + tid * 4);
        *(float4*)(xb + b * 512 + tid * 4) = v4;
    }
}

// ---------------------------------------------------------------------------
extern "C" void kernel_launch(void* const* d_in, const int* in_sizes, int n_in,
                              void* d_out, int out_size, void* d_ws, size_t ws_size,
                              hipStream_t stream)
{
    const float* hidden = (const float*)d_in[0];   // [64, 4096]
    const float* in_w   = (const float*)d_in[1];   // [512, 4096]
    const float* in_b   = (const float*)d_in[2];   // [512]
    const float* w_ih0  = (const float*)d_in[3];   // [1536, 512]
    const float* w_hh0  = (const float*)d_in[4];
    const float* b_ih0  = (const float*)d_in[5];
    const float* b_hh0  = (const float*)d_in[6];
    const float* w_ih1  = (const float*)d_in[7];
    const float* w_hh1  = (const float*)d_in[8];
    const float* b_ih1  = (const float*)d_in[9];
    const float* b_hh1  = (const float*)d_in[10];
    const float* embed  = (const float*)d_in[11];  // [32000, 512]
    const float* out_w  = (const float*)d_in[12];  // [32000, 512]
    float* out = (float*)d_out;                    // [64, 4, 32000]
    float* ws  = (float*)d_ws;

    // ws floats: hA[32768] hB[32768] xb[32768] gi[98304] gh[98304]
    //            pval[16000] pidx[16000]   (ipart reuses gi/gh region)
    float* hA   = ws;
    float* hB   = ws + 32768;
    float* xb   = ws + 65536;
    float* gi   = ws + 98304;
    float* gh   = gi + 98304;
    float* ipart= gi;                 // 8*32768 floats, used before gates
    float* pval = gh + 98304;         // 294912
    int*   pidx = (int*)(pval + 16000);

    k_inproj<<<32, 256, 0, stream>>>(hidden, in_w, ipart);
    k_reduce_inproj<<<128, 256, 0, stream>>>(ipart, in_b, hA, hB, xb);

    for (int step = 0; step < 4; ++step) {
        k_gates<<<24, 256, 0, stream>>>(xb, hA, w_ih0, w_hh0, gi, gh);
        k_combine<<<128, 256, 0, stream>>>(gi, gh, b_ih0, b_hh0, hA);
        k_gates<<<24, 256, 0, stream>>>(hA, hB, w_ih1, w_hh1, gi, gh);
        k_combine<<<128, 256, 0, stream>>>(gi, gh, b_ih1, b_hh1, hB);
        k_logits<<<250, 256, 0, stream>>>(hB, out_w, out, step, pval, pidx);
        k_reduce_embed<<<64, 256, 0, stream>>>(pval, pidx, embed, xb);
    }
}

// Round 4
// 384.763 us; speedup vs baseline: 1.6426x; 1.2319x over previous
//
#include <hip/hip_runtime.h>
#include <math.h>

// ReDrafterHead: B=64, H=4096, D=512, G3=1536, V=32000, STEPS=4
// Round 4: A-operands pre-split to swizzled bf16 hi/lo planes (writers emit
// them); GEMM A-staging via global_load_lds identity copy; 512-thread GEMM
// blocks (8 waves -> 2 waves/SIMD); gates K-split=2.

typedef __attribute__((ext_vector_type(8))) short short8;   // 8 bf16
typedef __attribute__((ext_vector_type(4))) float f32x4;

__device__ __forceinline__ unsigned short f2bf_rne(float x) {
    unsigned u = __float_as_uint(x);
    unsigned r = (u + 0x7fffu + ((u >> 16) & 1u)) >> 16;
    return (unsigned short)r;
}
// hi = truncate; lo = RNE of residual. 3-pass MFMA error ~2^-16 rel.
__device__ __forceinline__ void split2(float x, unsigned short& hi, unsigned short& lo) {
    unsigned u = __float_as_uint(x);
    hi = (unsigned short)(u >> 16);
    float r = x - __uint_as_float(u & 0xffff0000u);
    lo = f2bf_rne(r);
}

// store one element into swizzled bf16 hi/lo planes, row stride 512 elems.
// layout: elem d -> slice s=d>>6 (128B), chunk cl=(d>>3)&7 XOR (m&7), byte (d&7)*2
__device__ __forceinline__ void store_plane(unsigned short* hiP, unsigned short* loP,
                                            int m, int d, float v) {
    int s = d >> 6, cl = (d >> 3) & 7, e = d & 7;
    int off = m * 512 + s * 64 + ((cl ^ (m & 7)) * 8) + e;
    unsigned short hi, lo; split2(v, hi, lo);
    hiP[off] = hi; loP[off] = lo;
}

__device__ __forceinline__ void gload16(const void* g, void* lds) {
    __builtin_amdgcn_global_load_lds(
        (const __attribute__((address_space(1))) unsigned int*)g,
        (__attribute__((address_space(3))) unsigned int*)lds, 16, 0, 0);
}

// ---------------------------------------------------------------------------
// MFMA GEMM, 512 threads (8 waves). C[0..63][n0..n0+127] over k [k0,k0+klen).
// A: pre-split swizzled bf16 planes (row stride AstrideB bytes).
// W: fp32 [N][ldbK], split in-kernel. Wave wv owns cols [wv*16,(wv+1)*16).
// ---------------------------------------------------------------------------
#define LDTB 72   // B LDS row stride (ushorts)

template<bool ARGMAX>
__device__ __forceinline__ void mfma_gemm(
    const char* __restrict__ AH, const char* __restrict__ AL, int AstrideB,
    const float* __restrict__ W, int ldbK,
    int n0, int k0, int klen,
    float* __restrict__ C, int ldc,
    unsigned short* AsH, unsigned short* AsL,
    unsigned short* BsH, unsigned short* BsL,
    float* __restrict__ pval, int* __restrict__ pidx, int bx)
{
    const int tid  = threadIdx.x;
    const int wv   = tid >> 6;
    const int lane = tid & 63;
    const int lr   = lane & 15;
    const int lh   = lane >> 4;

    f32x4 acc[4];
#pragma unroll
    for (int i = 0; i < 4; ++i) acc[i] = (f32x4){0.f, 0.f, 0.f, 0.f};

    for (int kk = k0; kk < k0 + klen; kk += 64) {
        // ---- A tiles: identity copy of swizzled planes, 1 chunk/thread/plane
        {
            int m  = tid >> 3;
            int cp = tid & 7;
            const char* sH = AH + m * AstrideB + kk * 2 + cp * 16;
            const char* sL = AL + m * AstrideB + kk * 2 + cp * 16;
            gload16(sH, (char*)AsH + wv * 1024);
            gload16(sL, (char*)AsL + wv * 1024);
        }
        // ---- B tile: fp32 load + split, 4 float4/thread ----
#pragma unroll
        for (int r = 0; r < 4; ++r) {
            int idx = r * 512 + tid;      // 2048 float4 slots
            int n = idx >> 4;
            int q = idx & 15;
            float4 v = *(const float4*)(W + (n0 + n) * ldbK + kk + q * 4);
            unsigned short h0,h1,h2,h3,l0,l1,l2,l3;
            split2(v.x,h0,l0); split2(v.y,h1,l1); split2(v.z,h2,l2); split2(v.w,h3,l3);
            uint2 ph = make_uint2((unsigned)h0 | ((unsigned)h1 << 16),
                                  (unsigned)h2 | ((unsigned)h3 << 16));
            uint2 pl = make_uint2((unsigned)l0 | ((unsigned)l1 << 16),
                                  (unsigned)l2 | ((unsigned)l3 << 16));
            *(uint2*)(BsH + n * LDTB + q * 4) = ph;
            *(uint2*)(BsL + n * LDTB + q * 4) = pl;
        }
        __syncthreads();

#pragma unroll
        for (int kk2 = 0; kk2 < 2; ++kk2) {
            int aoff = lr * 64 + (((kk2 * 4 + lh) ^ (lr & 7)) * 8);
            short8 ah[4], al[4];
#pragma unroll
            for (int mt = 0; mt < 4; ++mt) {
                ah[mt] = *(const short8*)(AsH + mt * 1024 + aoff);
                al[mt] = *(const short8*)(AsL + mt * 1024 + aoff);
            }
            int boff = (wv * 16 + lr) * LDTB + kk2 * 32 + lh * 8;
            short8 bh = *(const short8*)(BsH + boff);
            short8 bl = *(const short8*)(BsL + boff);
#pragma unroll
            for (int mt = 0; mt < 4; ++mt) {
                acc[mt] = __builtin_amdgcn_mfma_f32_16x16x32_bf16(ah[mt], bh, acc[mt], 0, 0, 0);
                acc[mt] = __builtin_amdgcn_mfma_f32_16x16x32_bf16(ah[mt], bl, acc[mt], 0, 0, 0);
                acc[mt] = __builtin_amdgcn_mfma_f32_16x16x32_bf16(al[mt], bh, acc[mt], 0, 0, 0);
            }
        }
        __syncthreads();
    }

    // ---- epilogue: D mapping col=lane&15, row=(lane>>4)*4+i ----
#pragma unroll
    for (int mt = 0; mt < 4; ++mt)
#pragma unroll
        for (int i = 0; i < 4; ++i) {
            int m = mt * 16 + lh * 4 + i;
            C[m * ldc + n0 + wv * 16 + lr] = acc[mt][i];
        }

    if (ARGMAX) {
        float* sv = (float*)AsH;   // 8*64 floats
        int*   sc = (int*)AsL;
#pragma unroll
        for (int mt = 0; mt < 4; ++mt)
#pragma unroll
            for (int i = 0; i < 4; ++i) {
                float v = acc[mt][i];
                int   c = n0 + wv * 16 + lr;
#pragma unroll
                for (int msk = 1; msk < 16; msk <<= 1) {
                    float ov = __shfl_xor(v, msk, 64);
                    int   oc = __shfl_xor(c, msk, 64);
                    if (ov > v || (ov == v && oc < c)) { v = ov; c = oc; }
                }
                if (lr == 0) {
                    int row = mt * 16 + lh * 4 + i;
                    sv[wv * 64 + row] = v;
                    sc[wv * 64 + row] = c;
                }
            }
        __syncthreads();
        if (tid < 64) {
            float v = sv[tid]; int c = sc[tid];
#pragma unroll
            for (int w = 1; w < 8; ++w) {
                float ov = sv[w * 64 + tid]; int oc = sc[w * 64 + tid];
                if (ov > v) { v = ov; c = oc; }   // ascending col order -> first-occurrence
            }
            pval[bx * 64 + tid] = v;
            pidx[bx * 64 + tid] = c;
        }
    }
}

#define DECLARE_LDS() \
    __shared__ alignas(16) unsigned short AsH[64 * 64]; \
    __shared__ alignas(16) unsigned short AsL[64 * 64]; \
    __shared__ alignas(16) unsigned short BsH[128 * LDTB]; \
    __shared__ alignas(16) unsigned short BsL[128 * LDTB];

// ---------------------------------------------------------------------------
// split hidden[64,4096] fp32 -> swizzled bf16 planes (row stride 8192 B)
// ---------------------------------------------------------------------------
__global__ __launch_bounds__(256) void k_split_A(
    const float* __restrict__ hidden, char* __restrict__ hidH, char* __restrict__ hidL)
{
    int g = blockIdx.x * 256 + threadIdx.x;   // 32768 chunks
    int m = g >> 9;
    int cc = g & 511;
    int s = cc >> 3, cl = cc & 7;
    const float* src = hidden + m * 4096 + cc * 8;
    float4 v0 = *(const float4*)src;
    float4 v1 = *(const float4*)(src + 4);
    unsigned short h[8], l[8];
    split2(v0.x,h[0],l[0]); split2(v0.y,h[1],l[1]); split2(v0.z,h[2],l[2]); split2(v0.w,h[3],l[3]);
    split2(v1.x,h[4],l[4]); split2(v1.y,h[5],l[5]); split2(v1.z,h[6],l[6]); split2(v1.w,h[7],l[7]);
    uint4 ph = make_uint4((unsigned)h[0]|((unsigned)h[1]<<16), (unsigned)h[2]|((unsigned)h[3]<<16),
                          (unsigned)h[4]|((unsigned)h[5]<<16), (unsigned)h[6]|((unsigned)h[7]<<16));
    uint4 pl = make_uint4((unsigned)l[0]|((unsigned)l[1]<<16), (unsigned)l[2]|((unsigned)l[3]<<16),
                          (unsigned)l[4]|((unsigned)l[5]<<16), (unsigned)l[6]|((unsigned)l[7]<<16));
    int off = m * 8192 + s * 128 + ((cl ^ (m & 7)) * 16);
    *(uint4*)(hidH + off) = ph;
    *(uint4*)(hidL + off) = pl;
}

// ---------------------------------------------------------------------------
// in_proj: part[ks][64][512] = hidden @ in_w^T, 32 blocks (4 nt x 8 ks)
// ---------------------------------------------------------------------------
__global__ __launch_bounds__(512) void k_inproj(
    const char* __restrict__ hidH, const char* __restrict__ hidL,
    const float* __restrict__ W, float* __restrict__ part)
{
    DECLARE_LDS();
    int nt = blockIdx.x & 3;
    int ks = blockIdx.x >> 2;
    mfma_gemm<false>(hidH, hidL, 8192, W, 4096, nt * 128, ks * 512, 512,
                     part + ks * 32768, 512, AsH, AsL, BsH, BsL, nullptr, nullptr, 0);
}

__global__ __launch_bounds__(256) void k_reduce_inproj(
    const float* __restrict__ part, const float* __restrict__ bias,
    float* __restrict__ hA, float* __restrict__ hB,
    unsigned short* hAH, unsigned short* hAL,
    unsigned short* hBH, unsigned short* hBL,
    unsigned short* xH,  unsigned short* xL)
{
    int i = blockIdx.x * 256 + threadIdx.x;   // < 32768
    int b = i >> 9;
    int d = i & 511;
    float s = bias[d];
#pragma unroll
    for (int ks = 0; ks < 8; ++ks) s += part[ks * 32768 + i];
    hA[i] = s;
    hB[i] = s;
    store_plane(hAH, hAL, b, d, s);
    store_plane(hBH, hBL, b, d, s);
    store_plane(xH,  xL,  b, d, 0.f);
}

// ---------------------------------------------------------------------------
// GRU gates, K-split 2: 48 blocks (12 nt x 2 ks x 2 mat)
// ---------------------------------------------------------------------------
__global__ __launch_bounds__(512) void k_gates(
    const char* __restrict__ xH, const char* __restrict__ xL,
    const char* __restrict__ hH, const char* __restrict__ hL,
    const float* __restrict__ w_ih, const float* __restrict__ w_hh,
    float* __restrict__ gip, float* __restrict__ ghp)
{
    DECLARE_LDS();
    int bx = blockIdx.x;
    int nt = bx % 12;
    int ks = (bx / 12) & 1;
    int mat = bx / 24;
    const char* AH = mat ? hH : xH;
    const char* AL = mat ? hL : xL;
    const float* W = mat ? w_hh : w_ih;
    float* C = (mat ? ghp : gip) + ks * 98304;
    mfma_gemm<false>(AH, AL, 1024, W, 512, nt * 128, ks * 256, 256, C, 1536,
                     AsH, AsL, BsH, BsL, nullptr, nullptr, 0);
}

__global__ __launch_bounds__(256) void k_combine(
    const float* __restrict__ gip, const float* __restrict__ ghp,
    const float* __restrict__ b_ih, const float* __restrict__ b_hh,
    float* __restrict__ h, unsigned short* hH, unsigned short* hL)
{
    int i = blockIdx.x * 256 + threadIdx.x;   // < 32768
    int b = i >> 9;
    int d = i & 511;
    int base = b * 1536 + d;
    float ir = gip[base]         + gip[98304 + base]         + b_ih[d];
    float iz = gip[base + 512]   + gip[98304 + base + 512]   + b_ih[d + 512];
    float inn= gip[base + 1024]  + gip[98304 + base + 1024]  + b_ih[d + 1024];
    float hr = ghp[base]         + ghp[98304 + base]         + b_hh[d];
    float hz = ghp[base + 512]   + ghp[98304 + base + 512]   + b_hh[d + 512];
    float hn = ghp[base + 1024]  + ghp[98304 + base + 1024]  + b_hh[d + 1024];
    float r = 1.f / (1.f + expf(-(ir + hr)));
    float z = 1.f / (1.f + expf(-(iz + hz)));
    float n = tanhf(inn + r * hn);
    float hv = (1.f - z) * n + z * h[i];
    h[i] = hv;
    store_plane(hH, hL, b, d, hv);
}

// ---------------------------------------------------------------------------
// logits + fused per-block argmax partials. grid = 250.
// ---------------------------------------------------------------------------
__global__ __launch_bounds__(512) void k_logits(
    const char* __restrict__ hH, const char* __restrict__ hL,
    const float* __restrict__ W, float* __restrict__ out, int step,
    float* __restrict__ pval, int* __restrict__ pidx)
{
    DECLARE_LDS();
    mfma_gemm<true>(hH, hL, 1024, W, 512, blockIdx.x * 128, 0, 512,
                    out + step * 32000, 128000, AsH, AsL, BsH, BsL,
                    pval, pidx, blockIdx.x);
}

// ---------------------------------------------------------------------------
// reduce 250 argmax partials (np first-occurrence) + embed gather -> x planes
// ---------------------------------------------------------------------------
__global__ __launch_bounds__(256) void k_reduce_embed(
    const float* __restrict__ pval, const int* __restrict__ pidx,
    const float* __restrict__ embed, unsigned short* xH, unsigned short* xL)
{
    __shared__ float sv[256];
    __shared__ int   sc[256];
    const int b = blockIdx.x;
    const int tid = threadIdx.x;
    float v = -3.4e38f;
    int   c = 0x7fffffff;
    if (tid < 250) { v = pval[tid * 64 + b]; c = pidx[tid * 64 + b]; }
    sv[tid] = v; sc[tid] = c;
    __syncthreads();
    for (int s = 128; s > 0; s >>= 1) {
        if (tid < s) {
            float ov = sv[tid + s]; int oc = sc[tid + s];
            if (ov > sv[tid] || (ov == sv[tid] && oc < sc[tid])) { sv[tid] = ov; sc[tid] = oc; }
        }
        __syncthreads();
    }
    int tok = sc[0];
    for (int j = tid; j < 512; j += 256)
        store_plane(xH, xL, b, j, embed[tok * 512 + j]);
}

// ---------------------------------------------------------------------------
extern "C" void kernel_launch(void* const* d_in, const int* in_sizes, int n_in,
                              void* d_out, int out_size, void* d_ws, size_t ws_size,
                              hipStream_t stream)
{
    const float* hidden = (const float*)d_in[0];
    const float* in_w   = (const float*)d_in[1];
    const float* in_b   = (const float*)d_in[2];
    const float* w_ih0  = (const float*)d_in[3];
    const float* w_hh0  = (const float*)d_in[4];
    const float* b_ih0  = (const float*)d_in[5];
    const float* b_hh0  = (const float*)d_in[6];
    const float* w_ih1  = (const float*)d_in[7];
    const float* w_hh1  = (const float*)d_in[8];
    const float* b_ih1  = (const float*)d_in[9];
    const float* b_hh1  = (const float*)d_in[10];
    const float* embed  = (const float*)d_in[11];
    const float* out_w  = (const float*)d_in[12];
    float* out = (float*)d_out;                    // [64, 4, 32000]
    char*  ws  = (char*)d_ws;

    // ws layout (bytes)
    float* hA  = (float*)(ws + 0);            // 131072
    float* hB  = (float*)(ws + 131072);       // 131072
    unsigned short* xH  = (unsigned short*)(ws + 262144);   // 65536 each
    unsigned short* xL  = (unsigned short*)(ws + 327680);
    unsigned short* hAH = (unsigned short*)(ws + 393216);
    unsigned short* hAL = (unsigned short*)(ws + 458752);
    unsigned short* hBH = (unsigned short*)(ws + 524288);
    unsigned short* hBL = (unsigned short*)(ws + 589824);
    char* hidH = ws + 655360;                 // 524288
    char* hidL = ws + 1179648;                // 524288
    float* gip = (float*)(ws + 1703936);      // 2*98304 floats = 786432 B
    float* ghp = (float*)(ws + 2490368);      // 786432 B
    float* ipart = gip;                       // 8*32768 floats, used before gates
    float* pval = (float*)(ws + 3276800);     // 64000
    int*   pidx = (int*)  (ws + 3340800);     // 64000

    k_split_A<<<128, 256, 0, stream>>>(hidden, hidH, hidL);
    k_inproj<<<32, 512, 0, stream>>>(hidH, hidL, in_w, ipart);
    k_reduce_inproj<<<128, 256, 0, stream>>>(ipart, in_b, hA, hB,
                                             hAH, hAL, hBH, hBL, xH, xL);

    for (int step = 0; step < 4; ++step) {
        k_gates<<<48, 512, 0, stream>>>((char*)xH, (char*)xL, (char*)hAH, (char*)hAL,
                                        w_ih0, w_hh0, gip, ghp);
        k_combine<<<128, 256, 0, stream>>>(gip, ghp, b_ih0, b_hh0, hA, hAH, hAL);
        k_gates<<<48, 512, 0, stream>>>((char*)hAH, (char*)hAL, (char*)hBH, (char*)hBL,
                                        w_ih1, w_hh1, gip, ghp);
        k_combine<<<128, 256, 0, stream>>>(gip, ghp, b_ih1, b_hh1, hB, hBH, hBL);
        k_logits<<<250, 512, 0, stream>>>((char*)hBH, (char*)hBL, out_w, out, step, pval, pidx);
        k_reduce_embed<<<64, 256, 0, stream>>>(pval, pidx, embed, xH, xL);
    }
}